// Round 5
// baseline (14109.311 us; speedup 1.0000x reference)
//
#include <hip/hip_runtime.h>
#include <hip/hip_bf16.h>

// Problem constants
#define N0 150000
#define N1 75000
#define EE 200000
#define NAL 50000

typedef unsigned short u16;
using f32x4 = __attribute__((ext_vector_type(4))) float;
using u16x4 = __attribute__((ext_vector_type(4))) unsigned short;
using u16x8 = __attribute__((ext_vector_type(8))) unsigned short;

__device__ __forceinline__ u16 f2b(float f) {
  unsigned int b = __float_as_uint(f);
  b += 0x7FFFu + ((b >> 16) & 1u);   // RNE
  return (u16)(b >> 16);
}
__device__ __forceinline__ float b2f(u16 u) {
  return __uint_as_float(((unsigned int)u) << 16);
}

// ---------------- diagnostic sentinel (f32 out)
__global__ void sentinel_k(float* out, float val) {
  if (threadIdx.x == 0 && blockIdx.x == 0) out[0] = val;
}

// ---------------- input range check: any (unsigned)v >= limit sets bits in flag
__global__ __launch_bounds__(256) void check_k(const int* __restrict__ a, int n,
                                               unsigned limit, int bits,
                                               int* __restrict__ flag) {
  int i = blockIdx.x * 256 + threadIdx.x;
  if (i < n && (unsigned)a[i] >= limit) atomicOr(flag, bits);
}

// if any check fired, stamp a distinctive sentinel over out[0]
__global__ void flag_poke_k(const int* __restrict__ flag, float* __restrict__ out) {
  if (threadIdx.x == 0 && blockIdx.x == 0 && *flag != 0)
    out[0] = 1024.0f + 8.0f * (float)(*flag & 63);
}

// ---------------- transpose all 12+12 weight matrices to WT[m][k][o] f32
__global__ __launch_bounds__(256) void transpose_w(const float* __restrict__ Ws,
                                                   const float* __restrict__ Wt,
                                                   float* __restrict__ WTs,
                                                   float* __restrict__ WTt) {
  const int HALF = 12 * 16384;
  int idx = blockIdx.x * 256 + threadIdx.x;     // grid covers 2*HALF exactly
  int lidx = (idx < HALF) ? idx : idx - HALF;
  int o = lidx & 127, k = (lidx >> 7) & 127, m = lidx >> 14;
  if (idx < HALF) WTs[(size_t)m * 16384 + k * 128 + o] = Ws[(size_t)m * 16384 + o * 128 + k];
  else            WTt[(size_t)m * 16384 + k * 128 + o] = Wt[(size_t)m * 16384 + o * 128 + k];
}

// ---------------- embedding gather -> bf16 xs (id clamped defensively)
__global__ __launch_bounds__(256) void embed_k(const int* __restrict__ ids,
                                               const float* __restrict__ tab,
                                               u16* __restrict__ X, int N, unsigned vocab) {
  int idx = blockIdx.x * 256 + threadIdx.x;
  int v = idx >> 4;
  if (v >= N) return;
  int q = (idx & 15) << 3;
  unsigned id = (unsigned)ids[v];
  if (id >= vocab) id = 0;          // defensive; flags catch the misread
  const float* src = tab + (size_t)id * 128 + q;
  f32x4 x0 = *(const f32x4*)src;
  f32x4 x1 = *(const f32x4*)(src + 4);
  u16x8 o;
#pragma unroll
  for (int k = 0; k < 4; ++k) { o[k] = f2b(x0[k]); o[4 + k] = f2b(x1[k]); }
  *(u16x8*)(X + (size_t)v * 128 + q) = o;
}

// ---------------- VALU GEMM + bias: C[M,128]bf16 = X[M,128]bf16 @ WT[k][o] + b[o]
__global__ __launch_bounds__(256) void gemm_bias(const u16* __restrict__ X, int M,
                                                 const float* __restrict__ WT,
                                                 const float* __restrict__ bias,
                                                 u16* __restrict__ C) {
  __shared__ u16 Xl[64 * 128];
  const int t = threadIdx.x;
  const int row0 = blockIdx.x * 64;
#pragma unroll
  for (int u = 0; u < 4; ++u) {
    int c = t + 256 * u;                // chunk 0..1023 (8 elems each)
    int r = c >> 4, k8 = (c & 15) << 3;
    u16x8 v = {0, 0, 0, 0, 0, 0, 0, 0};
    if (row0 + r < M) v = *(const u16x8*)(X + (size_t)(row0 + r) * 128 + k8);
    *(u16x8*)&Xl[r * 128 + k8] = v;
  }
  __syncthreads();

  const int o4 = (t & 31) << 2;         // 4 consecutive output cols
  const int rg = t >> 5;                // row group (8 rows each)

  float acc[8][4];
#pragma unroll
  for (int r = 0; r < 8; ++r)
#pragma unroll
    for (int c = 0; c < 4; ++c) acc[r][c] = 0.f;

  for (int k0 = 0; k0 < 128; k0 += 8) {
    u16x8 xr[8];
#pragma unroll
    for (int r = 0; r < 8; ++r)
      xr[r] = *(const u16x8*)&Xl[(rg * 8 + r) * 128 + k0];
#pragma unroll
    for (int kk = 0; kk < 8; ++kk) {
      f32x4 wv = *(const f32x4*)(WT + (size_t)(k0 + kk) * 128 + o4);
#pragma unroll
      for (int r = 0; r < 8; ++r) {
        float xv = b2f(xr[r][kk]);
        acc[r][0] = fmaf(xv, wv[0], acc[r][0]);
        acc[r][1] = fmaf(xv, wv[1], acc[r][1]);
        acc[r][2] = fmaf(xv, wv[2], acc[r][2]);
        acc[r][3] = fmaf(xv, wv[3], acc[r][3]);
      }
    }
  }

  f32x4 bv = *(const f32x4*)(bias + o4);
#pragma unroll
  for (int r = 0; r < 8; ++r) {
    int row = row0 + rg * 8 + r;
    if (row < M) {
      u16x4 o;
#pragma unroll
      for (int c = 0; c < 4; ++c) o[c] = f2b(acc[r][c] + bv[c]);
      *(u16x4*)(C + (size_t)row * 128 + o4) = o;
    }
  }
}

// ---------------- per-edge atomic scatter-max over 8 features (reference-exact msg)
// Mb int-max vs 0-init == relu(segment_max(msg)) exactly; empty segment -> 0.
__global__ __launch_bounds__(256) void scatter_k(const int* __restrict__ es,
                                                 const u16* __restrict__ HS,
                                                 const u16* __restrict__ HD,
                                                 const float* __restrict__ esf,
                                                 int F, int* __restrict__ Mb,
                                                 unsigned Ms, unsigned Mt) {
  int e = blockIdx.x * 256 + threadIdx.x;
  if (e >= EE) return;
  int s = es[e], d = es[EE + e];
  int self = (s == d);
  if ((unsigned)s >= Ms) s = 0;      // defensive; flags catch the misread
  if ((unsigned)d >= Mt) d = 0;
  const float* ev = esf + (self ? 128 : 0) + F;
  u16x8 hs = *(const u16x8*)(HS + (size_t)s * 128 + F);
  u16x8 hd = *(const u16x8*)(HD + (size_t)d * 128 + F);
  int* mb = Mb + (size_t)d * 8;
#pragma unroll
  for (int f = 0; f < 8; ++f) {
    float msg = b2f(hs[f]) + b2f(hd[f]) + ev[f];
    atomicMax(mb + f, __float_as_int(msg));
  }
}

// ---------------- fold relu'd max chunk into next-layer xs
__global__ __launch_bounds__(256) void accum_k(const int* __restrict__ Mb,
                                               u16* __restrict__ xn,
                                               int F, int N, int add) {
  int d = blockIdx.x * 256 + threadIdx.x;
  if (d >= N) return;
  const int* mb = Mb + (size_t)d * 8;
  u16* xp = xn + (size_t)d * 128 + F;
  u16x8 o;
  if (add) {
    u16x8 prev = *(const u16x8*)xp;
#pragma unroll
    for (int f = 0; f < 8; ++f) o[f] = f2b(b2f(prev[f]) + __int_as_float(mb[f]));
  } else {
#pragma unroll
    for (int f = 0; f < 8; ++f) o[f] = f2b(__int_as_float(mb[f]));
  }
  *(u16x8*)xp = o;
}

// ---------------- decoder + softmax -> FLOAT32 out: [logits | softmax]
__global__ __launch_bounds__(256) void decoder_k(const u16* __restrict__ X,
                                                 const float* __restrict__ Wd,
                                                 const float* __restrict__ bd,
                                                 float* __restrict__ out) {
  int v = blockIdx.x * 256 + threadIdx.x;
  if (v >= N0) return;
  float a0 = bd[0], a1 = bd[1], a2 = bd[2];
  const u16* x = X + (size_t)v * 128;
#pragma unroll
  for (int k = 0; k < 128; k += 8) {
    u16x8 xv = *(const u16x8*)(x + k);
#pragma unroll
    for (int u = 0; u < 8; ++u) {
      float xf = b2f(xv[u]);
      a0 = fmaf(xf, Wd[k + u], a0);
      a1 = fmaf(xf, Wd[128 + k + u], a1);
      a2 = fmaf(xf, Wd[256 + k + u], a2);
    }
  }
  float mx = fmaxf(a0, fmaxf(a1, a2));
  float e0 = expf(a0 - mx), e1 = expf(a1 - mx), e2 = expf(a2 - mx);
  float inv = 1.f / (e0 + e1 + e2);
  size_t b = (size_t)v * 3;
  out[b + 0] = a0; out[b + 1] = a1; out[b + 2] = a2;
  size_t b2 = (size_t)N0 * 3 + b;
  out[b2 + 0] = e0 * inv; out[b2 + 1] = e1 * inv; out[b2 + 2] = e2 * inv;
}

extern "C" void kernel_launch(void* const* d_in, const int* in_sizes, int n_in,
                              void* d_out, int out_size, void* d_ws, size_t ws_size,
                              hipStream_t stream) {
  float* out = (float*)d_out;

  // ---- sentinel 500: input-size assumption check
  const int expect[15] = {N0, N1, 2 * EE, 2 * EE, 2 * EE, 2 * EE,
                          NAL * 128, 128, 196608, 1536, 196608, 1536,
                          3072, 384, 3};
  bool ok = (n_in == 15);
  if (ok) for (int i = 0; i < 15; ++i) ok = ok && (in_sizes[i] == expect[i]);
  if (!ok) { sentinel_k<<<1, 64, 0, stream>>>(out, 500.f); return; }

  const int* x0_ids = (const int*)d_in[0];
  const int* x1_ids = (const int*)d_in[1];
  const int* ess[4] = {(const int*)d_in[2], (const int*)d_in[3],
                       (const int*)d_in[4], (const int*)d_in[5]};
  const float* enc_al   = (const float*)d_in[6];
  const float* emb_test = (const float*)d_in[7];
  const float* W_tgt    = (const float*)d_in[8];
  const float* b_tgt    = (const float*)d_in[9];
  const float* W_src    = (const float*)d_in[10];
  const float* b_src    = (const float*)d_in[11];
  const float* emb_self = (const float*)d_in[12];
  const float* W_dec    = (const float*)d_in[13];
  const float* b_dec    = (const float*)d_in[14];

  // ---- bump allocator (~198.4 MB, proven safe)
  char* base = (char*)d_ws;
  size_t pos = 0;
  auto alloc = [&](size_t bytes) -> void* {
    void* r = base + pos;
    pos += (bytes + 255) & ~(size_t)255;
    return r;
  };
  u16* xs0 = (u16*)alloc((size_t)N0 * 128 * 2);
  u16* xs1 = (u16*)alloc((size_t)N1 * 128 * 2);
  u16* ys0 = (u16*)alloc((size_t)N0 * 128 * 2);
  u16* ys1 = (u16*)alloc((size_t)N1 * 128 * 2);
  u16* HS  = (u16*)alloc((size_t)N0 * 128 * 2);
  u16* HD  = (u16*)alloc((size_t)N0 * 128 * 2);
  float* WTs = (float*)alloc((size_t)12 * 16384 * 4);
  float* WTt = (float*)alloc((size_t)12 * 16384 * 4);
  int* Mb   = (int*)alloc((size_t)N0 * 8 * 4);
  int* flag = (int*)alloc(256);
  if (pos > ws_size) { sentinel_k<<<1, 64, 0, stream>>>(out, 900.f); return; }

  // ---- GPU-side input validation (bits -> absmax 1024+8*mask if any fire)
  hipMemsetAsync(flag, 0, 4, stream);
  const int CG2 = (2 * EE + 255) / 256, CG1 = (EE + 255) / 256;
  check_k<<<CG2, 256, 0, stream>>>(ess[0], 2 * EE, N0, 1, flag);
  check_k<<<CG1, 256, 0, stream>>>(ess[1], EE, N0, 2, flag);
  check_k<<<CG1, 256, 0, stream>>>(ess[1] + EE, EE, N1, 2, flag);
  check_k<<<CG1, 256, 0, stream>>>(ess[2], EE, N1, 4, flag);
  check_k<<<CG1, 256, 0, stream>>>(ess[2] + EE, EE, N0, 4, flag);
  check_k<<<CG2, 256, 0, stream>>>(ess[3], 2 * EE, N1, 8, flag);
  check_k<<<(N0 + 255) / 256, 256, 0, stream>>>(x0_ids, N0, NAL, 16, flag);
  check_k<<<(N1 + 255) / 256, 256, 0, stream>>>(x1_ids, N1, 1, 32, flag);

  // ---- one-time prep
  transpose_w<<<1536, 256, 0, stream>>>(W_src, W_tgt, WTs, WTt);
  embed_k<<<(N0 * 16 + 255) / 256, 256, 0, stream>>>(x0_ids, enc_al, xs0, N0, NAL);
  embed_k<<<(N1 * 16 + 255) / 256, 256, 0, stream>>>(x1_ids, emb_test, xs1, N1, 1);

  // ---- layers: reference-exact per-edge-type atomic scatter-max
  u16 *xc0 = xs0, *xc1 = xs1, *xn0 = ys0, *xn1 = ys1;
  const int SG = (EE + 255) / 256;
  for (int i = 0; i < 3; ++i) {
    for (int tt = 0; tt < 2; ++tt) {
      if (i == 2 && tt == 1) continue;   // type-1 output unused after last layer
      const int Mt = tt ? N1 : N0;
      u16* Xtgt = tt ? xc1 : xc0;
      u16* xn   = tt ? xn1 : xn0;
      for (int si = 0; si < 2; ++si) {
        const int j = tt + si * 2;       // T_TGTS=[0,1,0,1], T_SRCS=[0,0,1,1]
        const int ts = (j >= 2);
        const int Ms = ts ? N1 : N0;
        u16* Xsrc = ts ? xc1 : xc0;
        const size_t m = (size_t)(i * 4 + j);
        gemm_bias<<<(Ms + 63) / 64, 256, 0, stream>>>(Xsrc, Ms, WTs + m * 16384, b_src + m * 128, HS);
        gemm_bias<<<(Mt + 63) / 64, 256, 0, stream>>>(Xtgt, Mt, WTt + m * 16384, b_tgt + m * 128, HD);
        for (int fp = 0; fp < 16; ++fp) {
          hipMemsetAsync(Mb, 0, (size_t)Mt * 32, stream);
          scatter_k<<<SG, 256, 0, stream>>>(ess[j], HS, HD, emb_self + m * 256, fp * 8, Mb,
                                            (unsigned)Ms, (unsigned)Mt);
          accum_k<<<(Mt + 255) / 256, 256, 0, stream>>>(Mb, xn, fp * 8, Mt, si);
        }
      }
    }
    u16* tmp = xc0; xc0 = xn0; xn0 = tmp;
    tmp = xc1; xc1 = xn1; xn1 = tmp;
  }

  decoder_k<<<(N0 + 255) / 256, 256, 0, stream>>>(xc0, W_dec, b_dec, out);
  flag_poke_k<<<1, 64, 0, stream>>>(flag, out);
}

// Round 6
// 848.134 us; speedup vs baseline: 16.6357x; 16.6357x over previous
//
#include <hip/hip_runtime.h>
#include <hip/hip_bf16.h>

// Problem constants
#define N0 150000
#define N1 75000
#define EE 200000
#define NAL 50000

typedef unsigned short u16;
using s16x8 = __attribute__((ext_vector_type(8))) short;
using f32x4 = __attribute__((ext_vector_type(4))) float;
using u16x8 = __attribute__((ext_vector_type(8))) unsigned short;

__device__ __forceinline__ u16 f2b(float f) {
  unsigned int b = __float_as_uint(f);
  b += 0x7FFFu + ((b >> 16) & 1u);   // RNE
  return (u16)(b >> 16);
}
__device__ __forceinline__ float b2f(u16 u) {
  return __uint_as_float(((unsigned int)u) << 16);
}

// ---------------- diagnostic sentinel (f32 out)
__global__ void sentinel_k(float* out, float val) {
  if (threadIdx.x == 0 && blockIdx.x == 0) out[0] = val;
}

// ---------------- cast W_src / W_tgt to bf16, layout unchanged [m][o][k]
__global__ __launch_bounds__(256) void cast_w_k(const float* __restrict__ Ws,
                                                const float* __restrict__ Wt,
                                                u16* __restrict__ Bs,
                                                u16* __restrict__ Bt) {
  const int HALF = 12 * 16384;
  int idx = blockIdx.x * 256 + threadIdx.x;   // grid covers 2*HALF exactly
  if (idx < HALF) Bs[idx] = f2b(Ws[idx]);
  else            Bt[idx - HALF] = f2b(Wt[idx - HALF]);
}

// ---------------- embedding gather -> bf16 xs
__global__ __launch_bounds__(256) void embed_k(const int* __restrict__ ids,
                                               const float* __restrict__ tab,
                                               u16* __restrict__ X, int N, unsigned vocab) {
  int idx = blockIdx.x * 256 + threadIdx.x;
  int v = idx >> 4;
  if (v >= N) return;
  int q = (idx & 15) << 3;
  unsigned id = (unsigned)ids[v];
  if (id >= vocab) id = 0;          // defensive
  const float* src = tab + (size_t)id * 128 + q;
  f32x4 x0 = *(const f32x4*)src;
  f32x4 x1 = *(const f32x4*)(src + 4);
  u16x8 o;
#pragma unroll
  for (int k = 0; k < 4; ++k) { o[k] = f2b(x0[k]); o[4 + k] = f2b(x1[k]); }
  *(u16x8*)(X + (size_t)v * 128 + q) = o;
}

// ---------------- CSR build ----------
__global__ __launch_bounds__(256) void count_k(const int* __restrict__ dst,
                                               int* __restrict__ cnt) {
  int i = blockIdx.x * 256 + threadIdx.x;
  if (i < EE) atomicAdd(cnt + dst[i], 1);
}

__global__ __launch_bounds__(256) void scan1_k(const int* __restrict__ cnt,
                                               int* __restrict__ off,
                                               int* __restrict__ part, int N) {
  __shared__ int sh[256];
  int t = threadIdx.x, i = blockIdx.x * 256 + t;
  int v = (i < N) ? cnt[i] : 0;
  sh[t] = v; __syncthreads();
  for (int s = 1; s < 256; s <<= 1) {
    int x = (t >= s) ? sh[t - s] : 0; __syncthreads();
    sh[t] += x; __syncthreads();
  }
  if (i < N) off[i] = sh[t] - v;                 // exclusive within block
  if (t == 255) part[blockIdx.x] = sh[255];      // block total
}

__global__ __launch_bounds__(1024) void scan2_k(int* __restrict__ part, int n) {
  __shared__ int sh[1024];
  int t = threadIdx.x;
  int v = (t < n) ? part[t] : 0;
  sh[t] = v; __syncthreads();
  for (int s = 1; s < 1024; s <<= 1) {
    int x = (t >= s) ? sh[t - s] : 0; __syncthreads();
    sh[t] += x; __syncthreads();
  }
  if (t < n) part[t] = sh[t] - v;                // exclusive
}

__global__ __launch_bounds__(256) void scan3_k(int* __restrict__ off,
                                               const int* __restrict__ part, int N) {
  int i = blockIdx.x * 256 + threadIdx.x;
  if (i < N) off[i] += part[i >> 8];
  if (i == 0) off[N] = EE;
}

// einfo[pos] = src | (self_flag << 31); order within segment irrelevant for max
__global__ __launch_bounds__(256) void fill_k(const int* __restrict__ es,
                                              const int* __restrict__ off,
                                              int* __restrict__ cur,
                                              int* __restrict__ einfo) {
  int i = blockIdx.x * 256 + threadIdx.x;
  if (i >= EE) return;
  int s = es[i], d = es[EE + i];
  int pos = off[d] + atomicAdd(cur + d, 1);
  einfo[pos] = s | (s == d ? (int)0x80000000 : 0);
}

// ---------------- MFMA GEMM: C[M,128]bf16 = A[M,128]bf16 @ W[128o,128k]^T
// 64KB LDS, XOR chunk-swizzle (16B chunks, ch ^= row&7) -> conflict-free-ish.
__global__ __launch_bounds__(256, 2) void gemm128(const u16* __restrict__ A, int M,
                                                  const u16* __restrict__ B,
                                                  u16* __restrict__ C) {
  __shared__ u16 Al[128 * 128];
  __shared__ u16 Bl[128 * 128];
  const int t = threadIdx.x;
  const int row0 = blockIdx.x * 128;
#pragma unroll
  for (int u = 0; u < 8; ++u) {
    int c = t + 256 * u;                  // chunk id 0..2047 (16B chunks)
    int r = c >> 4, ch = c & 15;
    int sw = ch ^ (r & 7);
    if (row0 + r < M)
      *(u16x8*)&Al[r * 128 + sw * 8] = *(const u16x8*)(A + (size_t)(row0 + r) * 128 + ch * 8);
    *(u16x8*)&Bl[r * 128 + sw * 8] = *(const u16x8*)(B + r * 128 + ch * 8);
  }
  __syncthreads();

  const int w = t >> 6, lane = t & 63;
  const int lr = lane & 15, g = lane >> 4;

  f32x4 acc[2][8];
#pragma unroll
  for (int mr = 0; mr < 2; ++mr)
#pragma unroll
    for (int nf = 0; nf < 8; ++nf) acc[mr][nf] = f32x4{0.f, 0.f, 0.f, 0.f};

#pragma unroll
  for (int ks = 0; ks < 4; ++ks) {
    int chA = ks * 4 + g;                       // lane's K-chunk (8 bf16)
    int swz = (chA ^ (lr & 7)) * 8;             // rows below are all == lr (mod 8)
    s16x8 a0 = *(const s16x8*)&Al[(w * 32 + lr) * 128 + swz];
    s16x8 a1 = *(const s16x8*)&Al[(w * 32 + 16 + lr) * 128 + swz];
#pragma unroll
    for (int nf = 0; nf < 8; ++nf) {
      s16x8 b = *(const s16x8*)&Bl[(nf * 16 + lr) * 128 + swz];
      acc[0][nf] = __builtin_amdgcn_mfma_f32_16x16x32_bf16(a0, b, acc[0][nf], 0, 0, 0);
      acc[1][nf] = __builtin_amdgcn_mfma_f32_16x16x32_bf16(a1, b, acc[1][nf], 0, 0, 0);
    }
  }

#pragma unroll
  for (int nf = 0; nf < 8; ++nf) {
    int col = nf * 16 + lr;                     // C/D: col=lane&15, row=(lane>>4)*4+reg
#pragma unroll
    for (int mr = 0; mr < 2; ++mr) {
#pragma unroll
      for (int j = 0; j < 4; ++j) {
        int row = row0 + w * 32 + mr * 16 + g * 4 + j;
        if (row < M) C[(size_t)row * 128 + col] = f2b(acc[mr][nf][j]);
      }
    }
  }
}

// ---------------- fused CSR aggregation:
// Y[d] (+)= relu( HD[d] + (b_src+b_tgt) + max_e( HS[src_e] + e_self[flag_e] ) )
// empty segment -> -inf -> relu -> 0 (exactly relu(segment_max) semantics)
__global__ __launch_bounds__(256) void agg_k(const int* __restrict__ off,
                                             const int* __restrict__ einfo,
                                             const u16* __restrict__ HS,
                                             const u16* __restrict__ HD,
                                             const float* __restrict__ bs,
                                             const float* __restrict__ bt,
                                             const float* __restrict__ esf,  // [2][128]
                                             u16* __restrict__ Y, int N, int add) {
  int idx = blockIdx.x * 256 + threadIdx.x;
  int d = idx >> 4;                 // 16 threads per node, 8 features each
  if (d >= N) return;
  int f8 = (idx & 15) << 3;
  float ef0[8], ef1[8], bsum[8];
#pragma unroll
  for (int k = 0; k < 8; ++k) {
    ef0[k] = esf[f8 + k];
    ef1[k] = esf[128 + f8 + k];
    bsum[k] = bs[f8 + k] + bt[f8 + k];
  }
  float m[8];
#pragma unroll
  for (int k = 0; k < 8; ++k) m[k] = -INFINITY;
  int e0 = off[d], e1 = off[d + 1];
  if (e0 < 0) e0 = 0;               // defensive
  if (e1 > EE) e1 = EE;
  for (int e = e0; e < e1; ++e) {
    int info = einfo[e];
    int s = info & 0x7fffffff;
    u16x8 hv = *(const u16x8*)(HS + (size_t)s * 128 + f8);
#pragma unroll
    for (int k = 0; k < 8; ++k) {
      float ev = (info < 0) ? ef1[k] : ef0[k];
      m[k] = fmaxf(m[k], b2f(hv[k]) + ev);
    }
  }
  u16x8 hd = *(const u16x8*)(HD + (size_t)d * 128 + f8);
  u16x8 o;
  if (add) {
    u16x8 prev = *(const u16x8*)(Y + (size_t)d * 128 + f8);
#pragma unroll
    for (int k = 0; k < 8; ++k)
      o[k] = f2b(b2f(prev[k]) + fmaxf(b2f(hd[k]) + bsum[k] + m[k], 0.f));
  } else {
#pragma unroll
    for (int k = 0; k < 8; ++k)
      o[k] = f2b(fmaxf(b2f(hd[k]) + bsum[k] + m[k], 0.f));
  }
  *(u16x8*)(Y + (size_t)d * 128 + f8) = o;
}

// ---------------- decoder + softmax -> FLOAT32 out: [logits | softmax]
__global__ __launch_bounds__(256) void decoder_k(const u16* __restrict__ X,
                                                 const float* __restrict__ Wd,
                                                 const float* __restrict__ bd,
                                                 float* __restrict__ out) {
  int v = blockIdx.x * 256 + threadIdx.x;
  if (v >= N0) return;
  float a0 = bd[0], a1 = bd[1], a2 = bd[2];
  const u16* x = X + (size_t)v * 128;
#pragma unroll
  for (int k = 0; k < 128; k += 8) {
    u16x8 xv = *(const u16x8*)(x + k);
#pragma unroll
    for (int u = 0; u < 8; ++u) {
      float xf = b2f(xv[u]);
      a0 = fmaf(xf, Wd[k + u], a0);
      a1 = fmaf(xf, Wd[128 + k + u], a1);
      a2 = fmaf(xf, Wd[256 + k + u], a2);
    }
  }
  float mx = fmaxf(a0, fmaxf(a1, a2));
  float e0 = expf(a0 - mx), e1 = expf(a1 - mx), e2 = expf(a2 - mx);
  float inv = 1.f / (e0 + e1 + e2);
  size_t b = (size_t)v * 3;
  out[b + 0] = a0; out[b + 1] = a1; out[b + 2] = a2;
  size_t b2 = (size_t)N0 * 3 + b;
  out[b2 + 0] = e0 * inv; out[b2 + 1] = e1 * inv; out[b2 + 2] = e2 * inv;
}

extern "C" void kernel_launch(void* const* d_in, const int* in_sizes, int n_in,
                              void* d_out, int out_size, void* d_ws, size_t ws_size,
                              hipStream_t stream) {
  float* out = (float*)d_out;

  // ---- sentinel 500: input-size assumption check
  const int expect[15] = {N0, N1, 2 * EE, 2 * EE, 2 * EE, 2 * EE,
                          NAL * 128, 128, 196608, 1536, 196608, 1536,
                          3072, 384, 3};
  bool ok = (n_in == 15);
  if (ok) for (int i = 0; i < 15; ++i) ok = ok && (in_sizes[i] == expect[i]);
  if (!ok) { sentinel_k<<<1, 64, 0, stream>>>(out, 500.f); return; }

  const int* x0_ids = (const int*)d_in[0];
  const int* x1_ids = (const int*)d_in[1];
  const int* ess[4] = {(const int*)d_in[2], (const int*)d_in[3],
                       (const int*)d_in[4], (const int*)d_in[5]};
  const float* enc_al   = (const float*)d_in[6];
  const float* emb_test = (const float*)d_in[7];
  const float* W_tgt    = (const float*)d_in[8];
  const float* b_tgt    = (const float*)d_in[9];
  const float* W_src    = (const float*)d_in[10];
  const float* b_src    = (const float*)d_in[11];
  const float* emb_self = (const float*)d_in[12];
  const float* W_dec    = (const float*)d_in[13];
  const float* b_dec    = (const float*)d_in[14];

  // ---- bump allocator (~199.6 MB; <= ~201 MB proven to execute in r2/r3)
  char* base = (char*)d_ws;
  size_t pos = 0;
  auto alloc = [&](size_t bytes) -> void* {
    void* r = base + pos;
    pos += (bytes + 255) & ~(size_t)255;
    return r;
  };
  u16* xs0 = (u16*)alloc((size_t)N0 * 128 * 2);
  u16* xs1 = (u16*)alloc((size_t)N1 * 128 * 2);
  u16* ys0 = (u16*)alloc((size_t)N0 * 128 * 2);
  u16* ys1 = (u16*)alloc((size_t)N1 * 128 * 2);
  u16* HS  = (u16*)alloc((size_t)N0 * 128 * 2);
  u16* HD  = (u16*)alloc((size_t)N0 * 128 * 2);
  u16* BPs = (u16*)alloc((size_t)12 * 16384 * 2);
  u16* BPt = (u16*)alloc((size_t)12 * 16384 * 2);
  int ndst[4] = {N0, N1, N0, N1};
  int* offs[4]; int* einfos[4];
  for (int j = 0; j < 4; ++j) {
    offs[j]   = (int*)alloc((size_t)(ndst[j] + 1) * 4);
    einfos[j] = (int*)alloc((size_t)EE * 4);
  }
  int* counts = (int*)alloc((size_t)N0 * 4);
  int* cursor = (int*)alloc((size_t)N0 * 4);
  int* part   = (int*)alloc(1024 * 4);
  if (pos > ws_size) { sentinel_k<<<1, 64, 0, stream>>>(out, 900.f); return; }

  // ---- one-time prep
  cast_w_k<<<1536, 256, 0, stream>>>(W_src, W_tgt, BPs, BPt);
  embed_k<<<(N0 * 16 + 255) / 256, 256, 0, stream>>>(x0_ids, enc_al, xs0, N0, NAL);
  embed_k<<<(N1 * 16 + 255) / 256, 256, 0, stream>>>(x1_ids, emb_test, xs1, N1, 1);

  for (int j = 0; j < 4; ++j) {
    int N = ndst[j];
    int nb = (N + 255) / 256;
    hipMemsetAsync(counts, 0, (size_t)N * 4, stream);
    count_k<<<(EE + 255) / 256, 256, 0, stream>>>(ess[j] + EE, counts);
    scan1_k<<<nb, 256, 0, stream>>>(counts, offs[j], part, N);
    scan2_k<<<1, 1024, 0, stream>>>(part, nb);
    scan3_k<<<nb, 256, 0, stream>>>(offs[j], part, N);
    hipMemsetAsync(cursor, 0, (size_t)N * 4, stream);
    fill_k<<<(EE + 255) / 256, 256, 0, stream>>>(ess[j], offs[j], cursor, einfos[j]);
  }

  // ---- layers (ping-pong xs; h_dst & biases factored out of segment-max)
  u16 *xc0 = xs0, *xc1 = xs1, *xn0 = ys0, *xn1 = ys1;
  for (int i = 0; i < 3; ++i) {
    for (int tt = 0; tt < 2; ++tt) {
      if (i == 2 && tt == 1) continue;   // type-1 output unused after last layer
      const int Mt = tt ? N1 : N0;
      u16* Xtgt = tt ? xc1 : xc0;
      u16* xn   = tt ? xn1 : xn0;
      const int GA = (Mt * 16 + 255) / 256;
      for (int si = 0; si < 2; ++si) {
        const int j = tt + si * 2;       // T_TGTS=[0,1,0,1], T_SRCS=[0,0,1,1]
        const int ts = (j >= 2);
        const int Ms = ts ? N1 : N0;
        u16* Xsrc = ts ? xc1 : xc0;
        const size_t m = (size_t)(i * 4 + j);
        gemm128<<<(Ms + 127) / 128, 256, 0, stream>>>(Xsrc, Ms, BPs + m * 16384, HS);
        gemm128<<<(Mt + 127) / 128, 256, 0, stream>>>(Xtgt, Mt, BPt + m * 16384, HD);
        agg_k<<<GA, 256, 0, stream>>>(offs[j], einfos[j], HS, HD,
                                      b_src + m * 128, b_tgt + m * 128,
                                      emb_self + m * 256, xn, Mt, si);
      }
    }
    u16* tmp = xc0; xc0 = xn0; xn0 = tmp;
    tmp = xc1; xc1 = xn1; xn1 = tmp;
  }

  decoder_k<<<(N0 + 255) / 256, 256, 0, stream>>>(xc0, W_dec, b_dec, out);
}

// Round 7
// 629.684 us; speedup vs baseline: 22.4070x; 1.3469x over previous
//
#include <hip/hip_runtime.h>
#include <hip/hip_bf16.h>

// Problem constants
#define N0 150000
#define N1 75000
#define EE 200000
#define NAL 50000
#define NSEG (N0 + N1)
#define TOTE (4 * EE)

typedef unsigned short u16;
using s16x8 = __attribute__((ext_vector_type(8))) short;
using f32x4 = __attribute__((ext_vector_type(4))) float;
using u16x8 = __attribute__((ext_vector_type(8))) unsigned short;

__device__ __forceinline__ u16 f2b(float f) {
  unsigned int b = __float_as_uint(f);
  b += 0x7FFFu + ((b >> 16) & 1u);   // RNE
  return (u16)(b >> 16);
}
__device__ __forceinline__ float b2f(u16 u) {
  return __uint_as_float(((unsigned int)u) << 16);
}

// ---------------- diagnostic sentinel (f32 out)
__global__ void sentinel_k(float* out, float val) {
  if (threadIdx.x == 0 && blockIdx.x == 0) out[0] = val;
}

// ---------------- pack weights bf16: BP[i][slot][o][k]
// slot order: 0:Ws_j0 1:Wt_j0 2:Wt_j2 3:Ws_j2 4:Ws_j1 5:Ws_j3 6:Wt_j1 7:Wt_j3
__global__ __launch_bounds__(256) void prep_w(const float* __restrict__ Ws,
                                              const float* __restrict__ Wt,
                                              u16* __restrict__ BP) {
  int idx = blockIdx.x * 256 + threadIdx.x;   // grid covers 3*8*16384 exactly
  int mk = idx & 16383;
  int slot = (idx >> 14) & 7;
  int i = idx >> 17;
  const int ssel[8] = {1, 0, 0, 1, 1, 1, 0, 0};
  const int sj[8]   = {0, 0, 2, 2, 1, 3, 1, 3};
  const float* W = ssel[slot] ? Ws : Wt;
  BP[idx] = f2b(W[(size_t)(i * 4 + sj[slot]) * 16384 + mk]);
}

// ---------------- embedding gather -> bf16 xs
__global__ __launch_bounds__(256) void embed_k(const int* __restrict__ ids,
                                               const float* __restrict__ tab,
                                               u16* __restrict__ X, int N, unsigned vocab) {
  int idx = blockIdx.x * 256 + threadIdx.x;
  int v = idx >> 4;
  if (v >= N) return;
  int q = (idx & 15) << 3;
  unsigned id = (unsigned)ids[v];
  if (id >= vocab) id = 0;          // defensive
  const float* src = tab + (size_t)id * 128 + q;
  f32x4 x0 = *(const f32x4*)src;
  f32x4 x1 = *(const f32x4*)(src + 4);
  u16x8 o;
#pragma unroll
  for (int k = 0; k < 4; ++k) { o[k] = f2b(x0[k]); o[4 + k] = f2b(x1[k]); }
  *(u16x8*)(X + (size_t)v * 128 + q) = o;
}

// ---------------- merged CSR build over all 4 edge types ----------
// segment = dst (tgt type 0) or N0+dst (tgt type 1); si = j>>1; self = src==dst
__global__ __launch_bounds__(256) void count_all(const int* __restrict__ e0,
                                                 const int* __restrict__ e1,
                                                 const int* __restrict__ e2,
                                                 const int* __restrict__ e3,
                                                 int* __restrict__ cnt) {
  int i = blockIdx.x * 256 + threadIdx.x;
  if (i >= TOTE) return;
  int j = i / EE, r = i - j * EE;
  const int* es = (j == 0) ? e0 : (j == 1) ? e1 : (j == 2) ? e2 : e3;
  int dst = es[EE + r];
  int seg = (j & 1) ? N0 + dst : dst;
  atomicAdd(cnt + seg, 1);
}

__global__ __launch_bounds__(256) void scan1_k(const int* __restrict__ cnt,
                                               int* __restrict__ off,
                                               int* __restrict__ part, int N) {
  __shared__ int sh[256];
  int t = threadIdx.x, i = blockIdx.x * 256 + t;
  int v = (i < N) ? cnt[i] : 0;
  sh[t] = v; __syncthreads();
  for (int s = 1; s < 256; s <<= 1) {
    int x = (t >= s) ? sh[t - s] : 0; __syncthreads();
    sh[t] += x; __syncthreads();
  }
  if (i < N) off[i] = sh[t] - v;                 // exclusive within block
  if (t == 255) part[blockIdx.x] = sh[255];      // block total
}

__global__ __launch_bounds__(1024) void scan2_k(int* __restrict__ part, int n) {
  __shared__ int sh[1024];
  int t = threadIdx.x;
  int v = (t < n) ? part[t] : 0;
  sh[t] = v; __syncthreads();
  for (int s = 1; s < 1024; s <<= 1) {
    int x = (t >= s) ? sh[t - s] : 0; __syncthreads();
    sh[t] += x; __syncthreads();
  }
  if (t < n) part[t] = sh[t] - v;                // exclusive
}

__global__ __launch_bounds__(256) void scan3_k(int* __restrict__ off,
                                               const int* __restrict__ part, int N, int tot) {
  int i = blockIdx.x * 256 + threadIdx.x;
  if (i < N) off[i] += part[i >> 8];
  if (i == 0) off[N] = tot;
}

// einfo[pos] = src | (si<<30) | (self<<31)
__global__ __launch_bounds__(256) void fill_all(const int* __restrict__ e0,
                                                const int* __restrict__ e1,
                                                const int* __restrict__ e2,
                                                const int* __restrict__ e3,
                                                const int* __restrict__ off,
                                                int* __restrict__ cur,
                                                int* __restrict__ einfo) {
  int i = blockIdx.x * 256 + threadIdx.x;
  if (i >= TOTE) return;
  int j = i / EE, r = i - j * EE;
  const int* es = (j == 0) ? e0 : (j == 1) ? e1 : (j == 2) ? e2 : e3;
  int src = es[r], dst = es[EE + r];
  int seg = (j & 1) ? N0 + dst : dst;
  int info = src | ((j >> 1) << 30) | ((src == dst) ? (int)0x80000000 : 0);
  int pos = off[seg] + atomicAdd(cur + seg, 1);
  einfo[pos] = info;
}

// ---------------- multi-weight MFMA GEMM:
// A[M,128] staged once in LDS; loop over nw<=3 weight mats W[slot][o][k];
// Cw[M,128] bf16 per slot. XOR chunk-swizzle on both tiles.
__global__ __launch_bounds__(256, 2) void gemm_multi(const u16* __restrict__ A, int M,
                                                     const u16* __restrict__ W, int nw,
                                                     u16* __restrict__ C0,
                                                     u16* __restrict__ C1,
                                                     u16* __restrict__ C2) {
  __shared__ u16 Al[128 * 128];
  __shared__ u16 Bl[128 * 128];
  const int t = threadIdx.x;
  const int row0 = blockIdx.x * 128;
#pragma unroll
  for (int u = 0; u < 8; ++u) {
    int c = t + 256 * u;                  // chunk id 0..2047 (16B chunks)
    int r = c >> 4, ch = c & 15;
    int sw = ch ^ (r & 7);
    if (row0 + r < M)
      *(u16x8*)&Al[r * 128 + sw * 8] = *(const u16x8*)(A + (size_t)(row0 + r) * 128 + ch * 8);
  }

  const int w = t >> 6, lane = t & 63;
  const int lr = lane & 15, g = lane >> 4;

  for (int ws = 0; ws < nw; ++ws) {
    __syncthreads();                      // prev compute done / A visible
    const u16* Bsub = W + (size_t)ws * 16384;
#pragma unroll
    for (int u = 0; u < 8; ++u) {
      int c = t + 256 * u;
      int r = c >> 4, ch = c & 15;
      int sw = ch ^ (r & 7);
      *(u16x8*)&Bl[r * 128 + sw * 8] = *(const u16x8*)(Bsub + r * 128 + ch * 8);
    }
    __syncthreads();

    f32x4 acc[2][8];
#pragma unroll
    for (int mr = 0; mr < 2; ++mr)
#pragma unroll
      for (int nf = 0; nf < 8; ++nf) acc[mr][nf] = f32x4{0.f, 0.f, 0.f, 0.f};

#pragma unroll
    for (int ks = 0; ks < 4; ++ks) {
      int chA = ks * 4 + g;
      int swz = (chA ^ (lr & 7)) * 8;
      s16x8 a0 = *(const s16x8*)&Al[(w * 32 + lr) * 128 + swz];
      s16x8 a1 = *(const s16x8*)&Al[(w * 32 + 16 + lr) * 128 + swz];
#pragma unroll
      for (int nf = 0; nf < 8; ++nf) {
        s16x8 b = *(const s16x8*)&Bl[(nf * 16 + lr) * 128 + swz];
        acc[0][nf] = __builtin_amdgcn_mfma_f32_16x16x32_bf16(a0, b, acc[0][nf], 0, 0, 0);
        acc[1][nf] = __builtin_amdgcn_mfma_f32_16x16x32_bf16(a1, b, acc[1][nf], 0, 0, 0);
      }
    }

    u16* Cw = (ws == 0) ? C0 : ((ws == 1) ? C1 : C2);
#pragma unroll
    for (int nf = 0; nf < 8; ++nf) {
      int col = nf * 16 + lr;             // C/D: col=lane&15, row=(lane>>4)*4+reg
#pragma unroll
      for (int mr = 0; mr < 2; ++mr) {
#pragma unroll
        for (int j = 0; j < 4; ++j) {
          int row = row0 + w * 32 + mr * 16 + g * 4 + j;
          if (row < M) Cw[(size_t)row * 128 + col] = f2b(acc[mr][nf][j]);
        }
      }
    }
  }
}

// ---------------- fused dual-edge-type CSR aggregation:
// Y[d] = relu(HD0[d]+b0+max_{si=0}(HSA[s]+esf0[self]))
//      + relu(HD1[d]+b1+max_{si=1}(HSB[s]+esf1[self]))
__global__ __launch_bounds__(256) void agg2_k(const int* __restrict__ off,
                                              const int* __restrict__ einfo,
                                              int segbase,
                                              const u16* __restrict__ HSA,
                                              const u16* __restrict__ HSB,
                                              const u16* __restrict__ HD0,
                                              const u16* __restrict__ HD1,
                                              const float* __restrict__ bs0,
                                              const float* __restrict__ bt0,
                                              const float* __restrict__ bs1,
                                              const float* __restrict__ bt1,
                                              const float* __restrict__ esf0,
                                              const float* __restrict__ esf1,
                                              u16* __restrict__ Y, int N) {
  int idx = blockIdx.x * 256 + threadIdx.x;
  int d = idx >> 4;                 // 16 threads per node, 8 features each
  if (d >= N) return;
  int f8 = (idx & 15) << 3;
  float e0n[8], e0s[8], e1n[8], e1s[8];
#pragma unroll
  for (int k = 0; k < 8; ++k) {
    e0n[k] = esf0[f8 + k];  e0s[k] = esf0[128 + f8 + k];
    e1n[k] = esf1[f8 + k];  e1s[k] = esf1[128 + f8 + k];
  }
  float m0[8], m1[8];
#pragma unroll
  for (int k = 0; k < 8; ++k) { m0[k] = -INFINITY; m1[k] = -INFINITY; }
  int a = off[segbase + d], b = off[segbase + d + 1];
  for (int e = a; e < b; ++e) {
    int info = einfo[e];
    int s = info & 0x3FFFFFFF;
    int si = (info >> 30) & 1;
    bool self = (info < 0);
    const u16* hs = si ? HSB : HSA;
    u16x8 hv = *(const u16x8*)(hs + (size_t)s * 128 + f8);
#pragma unroll
    for (int k = 0; k < 8; ++k) {
      float ev = si ? (self ? e1s[k] : e1n[k]) : (self ? e0s[k] : e0n[k]);
      float v = b2f(hv[k]) + ev;
      m0[k] = fmaxf(m0[k], si ? -INFINITY : v);
      m1[k] = fmaxf(m1[k], si ? v : -INFINITY);
    }
  }
  u16x8 hd0 = *(const u16x8*)(HD0 + (size_t)d * 128 + f8);
  u16x8 hd1 = *(const u16x8*)(HD1 + (size_t)d * 128 + f8);
  u16x8 o;
#pragma unroll
  for (int k = 0; k < 8; ++k) {
    float r0 = fmaxf(b2f(hd0[k]) + bs0[f8 + k] + bt0[f8 + k] + m0[k], 0.f);
    float r1 = fmaxf(b2f(hd1[k]) + bs1[f8 + k] + bt1[f8 + k] + m1[k], 0.f);
    o[k] = f2b(r0 + r1);
  }
  *(u16x8*)(Y + (size_t)d * 128 + f8) = o;
}

// ---------------- decoder + softmax -> FLOAT32 out: [logits | softmax]
__global__ __launch_bounds__(256) void decoder_k(const u16* __restrict__ X,
                                                 const float* __restrict__ Wd,
                                                 const float* __restrict__ bd,
                                                 float* __restrict__ out) {
  int v = blockIdx.x * 256 + threadIdx.x;
  if (v >= N0) return;
  float a0 = bd[0], a1 = bd[1], a2 = bd[2];
  const u16* x = X + (size_t)v * 128;
#pragma unroll
  for (int k = 0; k < 128; k += 8) {
    u16x8 xv = *(const u16x8*)(x + k);
#pragma unroll
    for (int u = 0; u < 8; ++u) {
      float xf = b2f(xv[u]);
      a0 = fmaf(xf, Wd[k + u], a0);
      a1 = fmaf(xf, Wd[128 + k + u], a1);
      a2 = fmaf(xf, Wd[256 + k + u], a2);
    }
  }
  float mx = fmaxf(a0, fmaxf(a1, a2));
  float e0 = expf(a0 - mx), e1 = expf(a1 - mx), e2 = expf(a2 - mx);
  float inv = 1.f / (e0 + e1 + e2);
  size_t b = (size_t)v * 3;
  out[b + 0] = a0; out[b + 1] = a1; out[b + 2] = a2;
  size_t b2 = (size_t)N0 * 3 + b;
  out[b2 + 0] = e0 * inv; out[b2 + 1] = e1 * inv; out[b2 + 2] = e2 * inv;
}

extern "C" void kernel_launch(void* const* d_in, const int* in_sizes, int n_in,
                              void* d_out, int out_size, void* d_ws, size_t ws_size,
                              hipStream_t stream) {
  float* out = (float*)d_out;

  // ---- sentinel 500: input-size assumption check
  const int expect[15] = {N0, N1, 2 * EE, 2 * EE, 2 * EE, 2 * EE,
                          NAL * 128, 128, 196608, 1536, 196608, 1536,
                          3072, 384, 3};
  bool ok = (n_in == 15);
  if (ok) for (int i = 0; i < 15; ++i) ok = ok && (in_sizes[i] == expect[i]);
  if (!ok) { sentinel_k<<<1, 64, 0, stream>>>(out, 500.f); return; }

  const int* x0_ids = (const int*)d_in[0];
  const int* x1_ids = (const int*)d_in[1];
  const int* es0 = (const int*)d_in[2];
  const int* es1 = (const int*)d_in[3];
  const int* es2 = (const int*)d_in[4];
  const int* es3 = (const int*)d_in[5];
  const float* enc_al   = (const float*)d_in[6];
  const float* emb_test = (const float*)d_in[7];
  const float* W_tgt    = (const float*)d_in[8];
  const float* b_tgt    = (const float*)d_in[9];
  const float* W_src    = (const float*)d_in[10];
  const float* b_src    = (const float*)d_in[11];
  const float* emb_self = (const float*)d_in[12];
  const float* W_dec    = (const float*)d_in[13];
  const float* b_dec    = (const float*)d_in[14];

  // ---- bump allocator (~256.3 MB; ws_size = 256 MiB = 268.4 MB per r6 counters)
  char* base = (char*)d_ws;
  size_t pos = 0;
  auto alloc = [&](size_t bytes) -> void* {
    void* r = base + pos;
    pos += (bytes + 255) & ~(size_t)255;
    return r;
  };
  u16* xs0 = (u16*)alloc((size_t)N0 * 128 * 2);
  u16* xs1 = (u16*)alloc((size_t)N1 * 128 * 2);
  u16* ys0 = (u16*)alloc((size_t)N0 * 128 * 2);
  u16* ys1 = (u16*)alloc((size_t)N1 * 128 * 2);
  u16* P0  = (u16*)alloc((size_t)N0 * 128 * 2);
  u16* P1  = (u16*)alloc((size_t)N0 * 128 * 2);
  u16* P2  = (u16*)alloc((size_t)N0 * 128 * 2);
  u16* P3  = (u16*)alloc((size_t)N1 * 128 * 2);
  u16* BP  = (u16*)alloc((size_t)3 * 8 * 16384 * 2);
  int* off    = (int*)alloc((size_t)(NSEG + 1) * 4);
  int* einfo  = (int*)alloc((size_t)TOTE * 4);
  int* counts = (int*)alloc((size_t)NSEG * 4);
  int* cursor = (int*)alloc((size_t)NSEG * 4);
  int* part   = (int*)alloc(1024 * 4);
  if (pos > ws_size) { sentinel_k<<<1, 64, 0, stream>>>(out, 900.f); return; }

  // ---- one-time prep
  prep_w<<<1536, 256, 0, stream>>>(W_src, W_tgt, BP);
  embed_k<<<(N0 * 16 + 255) / 256, 256, 0, stream>>>(x0_ids, enc_al, xs0, N0, NAL);
  embed_k<<<(N1 * 16 + 255) / 256, 256, 0, stream>>>(x1_ids, emb_test, xs1, N1, 1);

  // ---- merged CSR build (once)
  const int EG = (TOTE + 255) / 256;            // 3125
  const int nb = (NSEG + 255) / 256;            // 879
  hipMemsetAsync(counts, 0, (size_t)NSEG * 4, stream);
  count_all<<<EG, 256, 0, stream>>>(es0, es1, es2, es3, counts);
  scan1_k<<<nb, 256, 0, stream>>>(counts, off, part, NSEG);
  scan2_k<<<1, 1024, 0, stream>>>(part, nb);
  scan3_k<<<nb, 256, 0, stream>>>(off, part, NSEG, TOTE);
  hipMemsetAsync(cursor, 0, (size_t)NSEG * 4, stream);
  fill_all<<<EG, 256, 0, stream>>>(es0, es1, es2, es3, off, cursor, einfo);

  // ---- layers
  const int G0 = (N0 + 127) / 128, G1 = (N1 + 127) / 128;
  const int GA0 = (N0 * 16 + 255) / 256, GA1 = (N1 * 16 + 255) / 256;
  u16 *xc0 = xs0, *xc1 = xs1, *xn0 = ys0, *xn1 = ys1;
  for (int i = 0; i < 3; ++i) {
    const u16* BPi = BP + (size_t)i * 8 * 16384;
    // target 0: j=0 (si0, src t0) + j=2 (si1, src t1)
    gemm_multi<<<G0, 256, 0, stream>>>(xc0, N0, BPi + 0 * 16384, 3, P0, P1, P2);
    gemm_multi<<<G1, 256, 0, stream>>>(xc1, N1, BPi + 3 * 16384, 1, P3, P3, P3);
    agg2_k<<<GA0, 256, 0, stream>>>(off, einfo, 0, P0, P3, P1, P2,
                                    b_src + (size_t)(i * 4 + 0) * 128, b_tgt + (size_t)(i * 4 + 0) * 128,
                                    b_src + (size_t)(i * 4 + 2) * 128, b_tgt + (size_t)(i * 4 + 2) * 128,
                                    emb_self + (size_t)(i * 4 + 0) * 256,
                                    emb_self + (size_t)(i * 4 + 2) * 256, xn0, N0);
    if (i < 2) {
      // target 1: j=1 (si0, src t0) + j=3 (si1, src t1)
      gemm_multi<<<G0, 256, 0, stream>>>(xc0, N0, BPi + 4 * 16384, 1, P0, P0, P0);
      gemm_multi<<<G1, 256, 0, stream>>>(xc1, N1, BPi + 5 * 16384, 3, P3, P1, P2);
      agg2_k<<<GA1, 256, 0, stream>>>(off, einfo, N0, P0, P3, P1, P2,
                                      b_src + (size_t)(i * 4 + 1) * 128, b_tgt + (size_t)(i * 4 + 1) * 128,
                                      b_src + (size_t)(i * 4 + 3) * 128, b_tgt + (size_t)(i * 4 + 3) * 128,
                                      emb_self + (size_t)(i * 4 + 1) * 256,
                                      emb_self + (size_t)(i * 4 + 3) * 256, xn1, N1);
    }
    u16* tmp = xc0; xc0 = xn0; xn0 = tmp;
    tmp = xc1; xc1 = xn1; xn1 = tmp;
  }

  decoder_k<<<(N0 + 255) / 256, 256, 0, stream>>>(xc0, W_dec, b_dec, out);
}